// Round 6
// baseline (6834.442 us; speedup 1.0000x reference)
//
#include <hip/hip_runtime.h>

typedef __attribute__((ext_vector_type(8))) short short8;
typedef __attribute__((ext_vector_type(4))) float f32x4;

#define B_   64
#define S_   512
#define V_   1400
#define VP_  1408
#define H_   256
#define G4_  1024
#define NC_  128
#define CH_  64    // time-chunk length (8 chunks of 64 steps)

__device__ __forceinline__ unsigned short f2bf(float f) {
    unsigned u = __builtin_bit_cast(unsigned, f);
    u += 0x7FFFu + ((u >> 16) & 1u);
    return (unsigned short)(u >> 16);
}
__device__ __forceinline__ float bf2f(unsigned short h) {
    unsigned u = ((unsigned)h) << 16;
    return __builtin_bit_cast(float, u);
}
__device__ __forceinline__ float fsig(float x) {
    x = fminf(fmaxf(x, -40.f), 40.f);
    float e = __builtin_amdgcn_exp2f(x * -1.44269504f);
    return __builtin_amdgcn_rcpf(1.0f + e);
}
__device__ __forceinline__ float ftanh(float x) {
    x = fminf(fmaxf(x, -40.f), 40.f);
    float e = __builtin_amdgcn_exp2f(x * 2.88539008f);
    return 1.0f - 2.0f * __builtin_amdgcn_rcpf(e + 1.0f);
}

// ---------------------------------------------------------------- K0: prep
__global__ void k0_prep(const float* __restrict__ emb,
                        const float* __restrict__ Wa1, const float* __restrict__ Wa2,
                        const float* __restrict__ Wd1, const float* __restrict__ Wd2,
                        const float* __restrict__ U1,  const float* __restrict__ U2,
                        const float* __restrict__ ba1, const float* __restrict__ bu1,
                        const float* __restrict__ ba2, const float* __restrict__ bu2,
                        const float* __restrict__ Wb,
                        unsigned short* __restrict__ embT, unsigned short* __restrict__ Wg,
                        unsigned short* __restrict__ Wd,   unsigned short* __restrict__ Ub,
                        unsigned short* __restrict__ Wbb,  float* __restrict__ bg) {
    int tid = blockIdx.x * blockDim.x + threadIdx.x;
    int np = gridDim.x * blockDim.x;
    for (int i = tid; i < 256 * VP_; i += np) {
        int n = i / VP_, k = i - n * VP_;
        embT[i] = (k < V_) ? f2bf(emb[k * H_ + n]) : (unsigned short)0;
    }
    for (int i = tid; i < G4_ * H_; i += np) {
        Wg[i] = f2bf(Wa1[i]); Wg[G4_ * H_ + i] = f2bf(Wa2[i]);
        Ub[i] = f2bf(U1[i]);  Ub[G4_ * H_ + i] = f2bf(U2[i]);
    }
    for (int i = tid; i < H_ * H_; i += np) {
        Wd[i] = f2bf(Wd1[i]); Wd[H_ * H_ + i] = f2bf(Wd2[i]); Wbb[i] = f2bf(Wb[i]);
    }
    for (int i = tid; i < G4_; i += np) {
        bg[i] = ba1[i] + bu1[i]; bg[G4_ + i] = ba2[i] + bu2[i];
    }
}

// ---------------------------------------------------------------- K1: embedded = inputs @ emb
__global__ __launch_bounds__(512, 2) void k1_embed(const float* __restrict__ inputs,
                                                   const unsigned short* __restrict__ embT,
                                                   unsigned short* __restrict__ embB) {
    const int tid = threadIdx.x;
    const int w = tid >> 6, ln = tid & 63, q = ln >> 4, l16 = ln & 15;
    const int mt = w >> 2, ng = (w & 3) * 4;
    const int Rbase = blockIdx.x * 32 + mt * 16;
    const float* arow = inputs + (long)(Rbase + l16) * V_;

    f32x4 acc[4];
    #pragma unroll
    for (int i = 0; i < 4; ++i) acc[i] = (f32x4){0.f, 0.f, 0.f, 0.f};

    for (int kt = 0; kt < 44; ++kt) {
        int k0 = kt * 32 + q * 8;
        short8 af;
        if (kt == 43 && q == 3) {
            #pragma unroll
            for (int j = 0; j < 8; ++j) af[j] = 0;
        } else {
            f32x4 x0 = *(const f32x4*)(arow + k0);
            f32x4 x1 = *(const f32x4*)(arow + k0 + 4);
            #pragma unroll
            for (int j = 0; j < 4; ++j) { af[j] = (short)f2bf(x0[j]); af[4 + j] = (short)f2bf(x1[j]); }
        }
        #pragma unroll
        for (int i = 0; i < 4; ++i) {
            short8 bf = *(const short8*)(embT + (long)((ng + i) * 16 + l16) * VP_ + k0);
            acc[i] = __builtin_amdgcn_mfma_f32_16x16x32_bf16(af, bf, acc[i], 0, 0, 0);
        }
    }
    #pragma unroll
    for (int i = 0; i < 4; ++i) {
        int col = (ng + i) * 16 + l16;
        #pragma unroll
        for (int j = 0; j < 4; ++j) {
            int R = Rbase + 4 * q + j;
            embB[(long)R * H_ + col] = f2bf(acc[i][j]);
        }
    }
}

// ---------------------------------------------------------------- K2: P chunk = embedded @ [U1;U2]^T + bg
// P row-major fp32: P[l][localrow' = sc*64 + b][gatecol 0..1023]; chunk covers steps [t0,t0+64).
__global__ __launch_bounds__(512, 2) void k2_pre(const unsigned short* __restrict__ embB,
                                                 const unsigned short* __restrict__ Ub,
                                                 const float* __restrict__ bg,
                                                 float* __restrict__ P, int t0) {
    const int tid = threadIdx.x;
    const int w = tid >> 6, ln = tid & 63, q = ln >> 4, l16 = ln & 15;
    const int rbase = blockIdx.x * 32;  // local row' in chunk, 0..4095

    short8 af[2][8];
    #pragma unroll
    for (int mt = 0; mt < 2; ++mt)
        #pragma unroll
        for (int kt = 0; kt < 8; ++kt) {
            int rp = rbase + mt * 16 + l16;
            int rg = t0 * 64 + rp;
            int b = rg & 63, s = rg >> 6;
            af[mt][kt] = *(const short8*)(embB + ((long)b * S_ + s) * H_ + kt * 32 + q * 8);
        }

    for (int i = 0; i < 16; ++i) {
        int nt2 = w * 16 + i;          // global gate-col tile 0..127
        int l = nt2 >> 6;
        int gcol = (nt2 & 63) * 16 + l16;   // col within lstm, 0..1023
        float bias = bg[nt2 * 16 + l16];
        short8 bf[8];
        #pragma unroll
        for (int kt = 0; kt < 8; ++kt)
            bf[kt] = *(const short8*)(Ub + (long)(nt2 * 16 + l16) * H_ + kt * 32 + q * 8);
        #pragma unroll
        for (int mt = 0; mt < 2; ++mt) {
            f32x4 acc = (f32x4){bias, bias, bias, bias};
            #pragma unroll
            for (int kt = 0; kt < 8; ++kt)
                acc = __builtin_amdgcn_mfma_f32_16x16x32_bf16(af[mt][kt], bf[kt], acc, 0, 0, 0);
            int rp0 = rbase + mt * 16;
            // C layout: row = 4q+j (within tile), col = l16 -> explicit row-major store
            float* dst = P + ((long)l * (CH_ * 64) + rp0 + 4 * q) * G4_ + gcol;
            #pragma unroll
            for (int j = 0; j < 4; ++j) dst[(long)j * G4_] = acc[j];
        }
    }
}

// ---------------------------------------------------------------- K3: time-LSTM chunk (64 steps)
__global__ __launch_bounds__(512, 2) void k3_lstm(const float* __restrict__ ts,
                                                  const unsigned short* __restrict__ W, // Wg || Wd
                                                  const float* __restrict__ bd1,
                                                  const float* __restrict__ bd2,
                                                  const float* __restrict__ P,
                                                  unsigned short* __restrict__ out1,
                                                  unsigned short* __restrict__ out2,
                                                  unsigned short* __restrict__ hst,
                                                  float* __restrict__ cst, int t0) {
    __shared__ unsigned short h_lds[16][264];
    __shared__ unsigned short c_lds[16][264];
    __shared__ float ts_lds[16][CH_];

    const int tid = threadIdx.x;
    const int w = tid >> 6, ln = tid & 63, q = ln >> 4, l16 = ln & 15;
    const int l = blockIdx.x >> 2, m = blockIdx.x & 3, b0 = m * 16;
    unsigned short* hbase = hst + (l * 4 + m) * 4096;
    float*          cbase = cst + (l * 4 + m) * 4096;

    const float* bdp = l ? bd2 : bd1;
    unsigned short* outp = l ? out2 : out1;
    const int colA = (2 * w) * 16 + l16;
    const int colB = (2 * w + 1) * 16 + l16;
    const float bdA = bdp[colA], bdB = bdp[colB];

    float cfA[4], cfB[4];
    if (t0 == 0) {
        for (int i = tid; i < 16 * 264; i += 512) { (&h_lds[0][0])[i] = 0; (&c_lds[0][0])[i] = 0; }
        #pragma unroll
        for (int j = 0; j < 4; ++j) { cfA[j] = 0.f; cfB[j] = 0.f; }
    } else {
        for (int i = tid; i < 4096; i += 512) {
            int r = i >> 8, cc = i & 255;
            h_lds[r][cc] = hbase[i];
            c_lds[r][cc] = f2bf(cbase[i]);
        }
        #pragma unroll
        for (int j = 0; j < 4; ++j) {
            cfA[j] = cbase[(4 * q + j) * 256 + colA];
            cfB[j] = cbase[(4 * q + j) * 256 + colB];
        }
    }
    for (int i = tid; i < 16 * CH_; i += 512) {
        int r = i >> 6, cc = i & (CH_ - 1);
        ts_lds[r][cc] = ts[(b0 + r) * S_ + t0 + cc];
    }

    int woff[10];
    #pragma unroll
    for (int g = 0; g < 4; ++g) {
        woff[g * 2 + 0] = (l * G4_ + g * H_ + colA) * H_ + q * 8;
        woff[g * 2 + 1] = (l * G4_ + g * H_ + colB) * H_ + q * 8;
    }
    woff[8] = 2 * G4_ * H_ + (l * H_ + colA) * H_ + q * 8;
    woff[9] = 2 * G4_ * H_ + (l * H_ + colB) * H_ + q * 8;

    // P addressing (row-major): row = l*4096 + t*64 + b0 + 4q + j, col = g*256 + (2w+c2)*16 + l16
    int pcol[8];
    #pragma unroll
    for (int g = 0; g < 4; ++g)
        #pragma unroll
        for (int c2 = 0; c2 < 2; ++c2)
            pcol[g * 2 + c2] = g * H_ + (2 * w + c2) * 16 + l16;
    const float* Pl = P + ((long)l * (CH_ * 64) + b0 + 4 * q) * G4_;

    __syncthreads();

    for (int t = 0; t < CH_; ++t) {
        __syncthreads();  // prev step's LDS writes visible
        const float* Pt = Pl + (long)t * (64 * G4_);

        // accumulator-init from P (explicit C-layout construction)
        f32x4 gacc[8];
        #pragma unroll
        for (int ti = 0; ti < 8; ++ti) {
            #pragma unroll
            for (int j = 0; j < 4; ++j) gacc[ti][j] = Pt[(long)j * G4_ + pcol[ti]];
        }

        // c_s1 pre-act: c @ W_d^T + b_d
        short8 ca[8];
        #pragma unroll
        for (int kt = 0; kt < 8; ++kt) ca[kt] = *(const short8*)&c_lds[l16][kt * 32 + q * 8];
        f32x4 dacc[2];
        dacc[0] = (f32x4){bdA, bdA, bdA, bdA};
        dacc[1] = (f32x4){bdB, bdB, bdB, bdB};
        #pragma unroll
        for (int c2 = 0; c2 < 2; ++c2)
            #pragma unroll
            for (int kt = 0; kt < 8; ++kt) {
                short8 bw = *(const short8*)(W + woff[8 + c2] + kt * 32);
                dacc[c2] = __builtin_amdgcn_mfma_f32_16x16x32_bf16(ca[kt], bw, dacc[c2], 0, 0, 0);
            }

        // gates pre-act: h @ W_all^T + P
        short8 ha[8];
        #pragma unroll
        for (int kt = 0; kt < 8; ++kt) ha[kt] = *(const short8*)&h_lds[l16][kt * 32 + q * 8];
        #pragma unroll
        for (int ti = 0; ti < 8; ++ti) {
            #pragma unroll
            for (int kt = 0; kt < 8; ++kt) {
                short8 bw = *(const short8*)(W + woff[ti] + kt * 32);
                gacc[ti] = __builtin_amdgcn_mfma_f32_16x16x32_bf16(ha[kt], bw, gacc[ti], 0, 0, 0);
            }
        }

        // elementwise
        float hnA[4], hnB[4];
        #pragma unroll
        for (int j = 0; j < 4; ++j) {
            float tv = ts_lds[4 * q + j][t];
            {
                float cs1 = ftanh(dacc[0][j]);
                float cadj = cfA[j] + cs1 * (tv - 1.0f);
                float fg = fsig(gacc[0][j]), ig = fsig(gacc[2][j]);
                float og = fsig(gacc[4][j]), cg = fsig(gacc[6][j]);
                float cn = fg * cadj + ig * cg;
                hnA[j] = og * ftanh(cn);
                cfA[j] = cn;
            }
            {
                float cs1 = ftanh(dacc[1][j]);
                float cadj = cfB[j] + cs1 * (tv - 1.0f);
                float fg = fsig(gacc[1][j]), ig = fsig(gacc[3][j]);
                float og = fsig(gacc[5][j]), cg = fsig(gacc[7][j]);
                float cn = fg * cadj + ig * cg;
                hnB[j] = og * ftanh(cn);
                cfB[j] = cn;
            }
        }

        __syncthreads();  // all LDS reads of this step done before overwrite
        #pragma unroll
        for (int j = 0; j < 4; ++j) {
            int r = 4 * q + j;
            h_lds[r][colA] = f2bf(hnA[j]);
            c_lds[r][colA] = f2bf(cfA[j]);
            h_lds[r][colB] = f2bf(hnB[j]);
            c_lds[r][colB] = f2bf(cfB[j]);
            long ob = ((long)(b0 + r) * S_ + (t0 + t)) * H_;
            outp[ob + colA] = f2bf(hnA[j]);
            outp[ob + colB] = f2bf(hnB[j]);
        }
    }

    // persist state for next chunk
    __syncthreads();
    for (int i = tid; i < 4096; i += 512) {
        int r = i >> 8, cc = i & 255;
        hbase[i] = h_lds[r][cc];
    }
    #pragma unroll
    for (int j = 0; j < 4; ++j) {
        cbase[(4 * q + j) * 256 + colA] = cfA[j];
        cbase[(4 * q + j) * 256 + colB] = cfB[j];
    }
}

// ---------------------------------------------------------------- K4a: scores + softmax -> alpha
__global__ __launch_bounds__(512) void k4a_alpha(const unsigned short* __restrict__ out1,
                                                 const float* __restrict__ wa,
                                                 float* __restrict__ alpha) {
    __shared__ float sc[512];
    __shared__ float red[512];
    const int b = blockIdx.x, tid = threadIdx.x;
    const int w = tid >> 6, ln = tid & 63;
    f32x4 wv = *(const f32x4*)(wa + ln * 4);
    for (int i = 0; i < 64; ++i) {
        int s = w * 64 + i;
        const unsigned short* row = out1 + ((long)b * S_ + s) * H_ + ln * 4;
        float d = bf2f(row[0]) * wv[0] + bf2f(row[1]) * wv[1] +
                  bf2f(row[2]) * wv[2] + bf2f(row[3]) * wv[3];
        #pragma unroll
        for (int off = 32; off; off >>= 1) d += __shfl_xor(d, off);
        if (ln == 0) sc[s] = d;
    }
    __syncthreads();
    float v = sc[tid];
    red[tid] = v;
    for (int st = 256; st; st >>= 1) {
        __syncthreads();
        if (tid < st) red[tid] = fmaxf(red[tid], red[tid + st]);
    }
    __syncthreads();
    float M = red[0];
    __syncthreads();
    float e = __builtin_amdgcn_exp2f((v - M) * 1.44269504f);
    red[tid] = e;
    for (int st = 256; st; st >>= 1) {
        __syncthreads();
        if (tid < st) red[tid] += red[tid + st];
    }
    __syncthreads();
    alpha[b * S_ + tid] = e * __builtin_amdgcn_rcpf(red[0]);
}

// ---------------------------------------------------------------- K4b: Beta=tanh(out2@Wb^T); ctx = sum_s emb*Beta*alpha
__global__ __launch_bounds__(512, 2) void k4b_ctx(const unsigned short* __restrict__ out2,
                                                  const unsigned short* __restrict__ Wbb,
                                                  const unsigned short* __restrict__ embB,
                                                  const float* __restrict__ alpha,
                                                  float* __restrict__ ctx) {
    __shared__ float cbuf[32][256];
    const int b = blockIdx.x, tid = threadIdx.x;
    const int w = tid >> 6, ln = tid & 63, q = ln >> 4, l16 = ln & 15;

    float cp[16];
    #pragma unroll
    for (int nt = 0; nt < 16; ++nt) cp[nt] = 0.f;

    for (int i = 0; i < 4; ++i) {
        int mt = w * 4 + i;
        short8 af[8];
        #pragma unroll
        for (int kt = 0; kt < 8; ++kt)
            af[kt] = *(const short8*)(out2 + ((long)b * S_ + mt * 16 + l16) * H_ + kt * 32 + q * 8);
        float al[4];
        #pragma unroll
        for (int j = 0; j < 4; ++j) al[j] = alpha[b * S_ + mt * 16 + 4 * q + j];
        for (int nt = 0; nt < 16; ++nt) {
            f32x4 acc = (f32x4){0.f, 0.f, 0.f, 0.f};
            #pragma unroll
            for (int kt = 0; kt < 8; ++kt) {
                short8 bf = *(const short8*)(Wbb + (long)(nt * 16 + l16) * H_ + kt * 32 + q * 8);
                acc = __builtin_amdgcn_mfma_f32_16x16x32_bf16(af[kt], bf, acc, 0, 0, 0);
            }
            #pragma unroll
            for (int j = 0; j < 4; ++j) {
                int s = mt * 16 + 4 * q + j;
                float beta = ftanh(acc[j]);
                float ev = bf2f(embB[((long)b * S_ + s) * H_ + nt * 16 + l16]);
                cp[nt] += beta * al[j] * ev;
            }
        }
    }
    #pragma unroll
    for (int nt = 0; nt < 16; ++nt) cbuf[w * 4 + q][nt * 16 + l16] = cp[nt];
    __syncthreads();
    if (tid < 256) {
        float sum = 0.f;
        for (int i = 0; i < 32; ++i) sum += cbuf[i][tid];
        ctx[b * H_ + tid] = sum;
    }
}

// ---------------------------------------------------------------- K4c: out = ctx @ W_out^T
__global__ void k4c_out(const float* __restrict__ ctx, const float* __restrict__ Wout,
                        float* __restrict__ out) {
    int b = blockIdx.x, n = threadIdx.x;
    const f32x4* cr = (const f32x4*)(ctx + b * H_);
    const f32x4* wr = (const f32x4*)(Wout + n * H_);
    float acc = 0.f;
    #pragma unroll 8
    for (int i = 0; i < 64; ++i) {
        f32x4 c = cr[i], ww = wr[i];
        acc += c[0] * ww[0] + c[1] * ww[1] + c[2] * ww[2] + c[3] * ww[3];
    }
    out[b * NC_ + n] = acc;
}

// ---------------------------------------------------------------- launch
extern "C" void kernel_launch(void* const* d_in, const int* in_sizes, int n_in,
                              void* d_out, int out_size, void* d_ws, size_t ws_size,
                              hipStream_t stream) {
    (void)in_sizes; (void)n_in; (void)out_size; (void)ws_size;
    const float* inputs = (const float*)d_in[0];
    const float* tsp    = (const float*)d_in[1];
    const float* emb    = (const float*)d_in[2];
    const float* Wa1 = (const float*)d_in[3];  const float* ba1 = (const float*)d_in[4];
    const float* U1  = (const float*)d_in[5];  const float* bu1 = (const float*)d_in[6];
    const float* Wd1 = (const float*)d_in[7];  const float* bd1 = (const float*)d_in[8];
    const float* Wa2 = (const float*)d_in[9];  const float* ba2 = (const float*)d_in[10];
    const float* U2  = (const float*)d_in[11]; const float* bu2 = (const float*)d_in[12];
    const float* Wd2 = (const float*)d_in[13]; const float* bd2 = (const float*)d_in[14];
    const float* wa  = (const float*)d_in[15];
    const float* Wb  = (const float*)d_in[16];
    const float* Wout = (const float*)d_in[17];
    float* out = (float*)d_out;

    // CORRECTED workspace map (round-5 post-mortem: out1/out2 are 64*512*256*2B
    // = 16,777,216 bytes each — previous rounds allocated half that, so out2
    // stomped out1's upper half and the state/alpha/ctx buffers).
    char* ws = (char*)d_ws;
    unsigned short* embT = (unsigned short*)(ws + 0);            //    720,896
    unsigned short* Wg   = (unsigned short*)(ws + 720896);       //  1,048,576 (Wd must follow)
    unsigned short* Wd   = (unsigned short*)(ws + 1769472);      //    262,144
    unsigned short* Ub   = (unsigned short*)(ws + 2031616);      //  1,048,576
    unsigned short* Wbb  = (unsigned short*)(ws + 3080192);      //    131,072
    float*          bgp  = (float*)(ws + 3211264);               //      8,192
    unsigned short* embB = (unsigned short*)(ws + 3219456);      // 16,777,216
    float*          P    = (float*)(ws + 19996672);              // 33,554,432 (64-step chunk)
    unsigned short* out1 = (unsigned short*)(ws + 53551104);     // 16,777,216
    unsigned short* out2 = (unsigned short*)(ws + 70328320);     // 16,777,216
    unsigned short* hst  = (unsigned short*)(ws + 87105536);     //     65,536
    float*          cst  = (float*)(ws + 87171072);              //    131,072
    float*          alp  = (float*)(ws + 87302144);              //    131,072
    float*          ctx  = (float*)(ws + 87433216);              //     65,536
    // total: 87,498,752 bytes (~83.4 MiB)

    hipLaunchKernelGGL(k0_prep, dim3(256), dim3(256), 0, stream,
                       emb, Wa1, Wa2, Wd1, Wd2, U1, U2, ba1, bu1, ba2, bu2, Wb,
                       embT, Wg, Wd, Ub, Wbb, bgp);
    hipLaunchKernelGGL(k1_embed, dim3(1024), dim3(512), 0, stream, inputs, embT, embB);
    for (int c = 0; c < 8; ++c) {
        hipLaunchKernelGGL(k2_pre, dim3(128), dim3(512), 0, stream, embB, Ub, bgp, P, c * CH_);
        hipLaunchKernelGGL(k3_lstm, dim3(8), dim3(512), 0, stream, tsp, Wg, bd1, bd2, P,
                           out1, out2, hst, cst, c * CH_);
    }
    hipLaunchKernelGGL(k4a_alpha, dim3(64), dim3(512), 0, stream, out1, wa, alp);
    hipLaunchKernelGGL(k4b_ctx, dim3(64), dim3(512), 0, stream, out2, Wbb, embB, alp, ctx);
    hipLaunchKernelGGL(k4c_out, dim3(64), dim3(128), 0, stream, ctx, Wout, out);
}